// Round 1
// baseline (88.664 us; speedup 1.0000x reference)
//
#include <hip/hip_runtime.h>

#define NN 177
#define OUTC 128
#define NEG 0.2f

// monotone float -> unsigned encoding (for atomicMax on floats)
__device__ __forceinline__ unsigned encf(float f) {
    unsigned b = __float_as_uint(f);
    return (b & 0x80000000u) ? ~b : (b | 0x80000000u);
}
__device__ __forceinline__ float decf(unsigned k) {
    unsigned b = (k & 0x80000000u) ? (k ^ 0x80000000u) : ~k;
    return __uint_as_float(b);
}

// K1: h = x @ weight  [177,128]; a_i[n] = h[n]·att[0:128]; a_j[n] = h[n]·att[128:256]
__global__ void k_node(const float* __restrict__ x, const float* __restrict__ w,
                       const float* __restrict__ att, float* __restrict__ h,
                       float* __restrict__ ai, float* __restrict__ aj) {
    int n = blockIdx.x, c = threadIdx.x;
    __shared__ float xl[128];
    __shared__ float r0[128], r1[128];
    xl[c] = x[n * 128 + c];
    __syncthreads();
    float acc = 0.f;
#pragma unroll 8
    for (int k = 0; k < 128; ++k) acc += xl[k] * w[k * 128 + c];
    h[n * 128 + c] = acc;
    r0[c] = acc * att[c];
    r1[c] = acc * att[128 + c];
    __syncthreads();
    for (int off = 64; off > 0; off >>= 1) {
        if (c < off) { r0[c] += r0[c + off]; r1[c] += r1[c + off]; }
        __syncthreads();
    }
    if (c == 0) { ai[n] = r0[0]; aj[n] = r1[0]; }
}

// K1b: G = h @ edge_update1[0:128,:]   [177,128]
__global__ void k_g(const float* __restrict__ h, const float* __restrict__ eu,
                    float* __restrict__ G) {
    int n = blockIdx.x, c = threadIdx.x;
    __shared__ float hl[128];
    hl[c] = h[n * 128 + c];
    __syncthreads();
    float acc = 0.f;
#pragma unroll 8
    for (int k = 0; k < 128; ++k) acc += hl[k] * eu[k * 128 + c];
    G[n * 128 + c] = acc;
}

// K2: per-edge leaky-relu logit, segment max over dst (LDS pre-reduce, then global)
__global__ void k_max(const int* __restrict__ ei, const float* __restrict__ ea,
                      const float* __restrict__ ai, const float* __restrict__ aj,
                      const float* __restrict__ att, unsigned* __restrict__ gmax, int E) {
    __shared__ float ail[NN], ajl[NN];
    __shared__ unsigned lmax[NN];
    int tid = threadIdx.x;
    for (int i = tid; i < NN; i += blockDim.x) {
        ail[i] = ai[i]; ajl[i] = aj[i]; lmax[i] = 0u;
    }
    float cc = att[2 * OUTC];
    __syncthreads();
    int stride = gridDim.x * blockDim.x;
    for (int e = blockIdx.x * blockDim.x + tid; e < E; e += stride) {
        int s = ei[e];
        int d = ei[E + e];
        float t = ail[d] + ajl[s] + cc * ea[e];
        t = (t > 0.f) ? t : NEG * t;
        atomicMax(&lmax[d], encf(t));
    }
    __syncthreads();
    for (int i = tid; i < NN; i += blockDim.x) atomicMax(&gmax[i], lmax[i]);
}

// K3: per-edge exp, accumulate W[dst][src], esum[dst], wlast[dst]
__global__ void k_acc(const int* __restrict__ ei, const float* __restrict__ ea,
                      const float* __restrict__ ai, const float* __restrict__ aj,
                      const float* __restrict__ att, const unsigned* __restrict__ gmax,
                      float* __restrict__ W, float* __restrict__ esum,
                      float* __restrict__ wlast, int E) {
    __shared__ float ail[NN], ajl[NN], amx[NN], lsum[NN], llast[NN];
    int tid = threadIdx.x;
    for (int i = tid; i < NN; i += blockDim.x) {
        ail[i] = ai[i]; ajl[i] = aj[i]; amx[i] = decf(gmax[i]);
        lsum[i] = 0.f; llast[i] = 0.f;
    }
    float cc = att[2 * OUTC];
    __syncthreads();
    int stride = gridDim.x * blockDim.x;
    for (int e = blockIdx.x * blockDim.x + tid; e < E; e += stride) {
        int s = ei[e];
        int d = ei[E + e];
        float eav = ea[e];
        float t = ail[d] + ajl[s] + cc * eav;
        t = (t > 0.f) ? t : NEG * t;
        float ev = __expf(t - amx[d]);
        atomicAdd(&lsum[d], ev);          // LDS
        atomicAdd(&llast[d], ev * eav);   // LDS
        unsafeAtomicAdd(&W[d * NN + s], ev);  // global, low contention (~16/cell)
    }
    __syncthreads();
    for (int i = tid; i < NN; i += blockDim.x) {
        unsafeAtomicAdd(&esum[i], lsum[i]);
        unsafeAtomicAdd(&wlast[i], llast[i]);
    }
}

// K4: out[n][c] = (W[n,:]@G[:,c] + wlast[n]*eu[128,c]) / (esum[n]+1e-16) + bias[c]
__global__ void k_out(const float* __restrict__ W, const float* __restrict__ G,
                      const float* __restrict__ wlast, const float* __restrict__ esum,
                      const float* __restrict__ eu, const float* __restrict__ bias,
                      float* __restrict__ out) {
    int n = blockIdx.x, c = threadIdx.x;
    __shared__ float wl[NN];
    for (int i = c; i < NN; i += 128) wl[i] = W[n * NN + i];
    __syncthreads();
    float acc = 0.f;
#pragma unroll 4
    for (int s = 0; s < NN; ++s) acc += wl[s] * G[s * 128 + c];
    float denom = esum[n] + 1e-16f;
    out[n * 128 + c] = (acc + wlast[n] * eu[128 * 128 + c]) / denom + bias[c];
}

extern "C" void kernel_launch(void* const* d_in, const int* in_sizes, int n_in,
                              void* d_out, int out_size, void* d_ws, size_t ws_size,
                              hipStream_t stream) {
    const float* x     = (const float*)d_in[0];
    const float* eattr = (const float*)d_in[1];
    const float* w     = (const float*)d_in[2];
    const float* att   = (const float*)d_in[3];
    const float* eu    = (const float*)d_in[4];
    const float* bias  = (const float*)d_in[5];
    const int*   ei    = (const int*)d_in[6];
    int E = in_sizes[6] / 2;

    float* ws = (float*)d_ws;
    // layout (floats): [W 31329 ->pad 31424][esum 192][wlast 192][gmax 192][h 22656][G 22656][ai 192][aj 192]
    float*    W     = ws;
    float*    esum  = ws + 31424;
    float*    wlast = ws + 31616;
    unsigned* gmax  = (unsigned*)(ws + 31808);
    float*    h     = ws + 32000;
    float*    G     = h + 22656;
    float*    ai    = G + 22656;
    float*    aj    = ai + 192;

    // zero W/esum/wlast/gmax every launch (gmax=0 is the encoded minimum)
    hipMemsetAsync(d_ws, 0, 32000 * sizeof(float), stream);

    k_node<<<NN, 128, 0, stream>>>(x, w, att, h, ai, aj);
    k_g<<<NN, 128, 0, stream>>>(h, eu, G);
    k_max<<<512, 256, 0, stream>>>(ei, eattr, ai, aj, att, gmax, E);
    k_acc<<<512, 256, 0, stream>>>(ei, eattr, ai, aj, att, gmax, W, esum, wlast, E);
    k_out<<<NN, 128, 0, stream>>>(W, G, wlast, esum, eu, bias, (float*)d_out);
}

// Round 2
// 78.751 us; speedup vs baseline: 1.1259x; 1.1259x over previous
//
#include <hip/hip_runtime.h>

#define NN 177
#define OUTC 128
#define NEG 0.2f
#define EDGE_BLOCKS 256
#define EDGE_THREADS 256

// Workspace layout (floats):
//   W     : [0, 31329)        (177*177 attention-weight matrix, padded to 31360)
//   wlast : [31360, 31537)    (padded to 31552)   -- zero region = [0, 31552)
//   ai    : [31552, 31729)    (pad 31744)
//   aj    : [31744, 31921)    (pad 31936)
//   G     : [31936, 54592)    (177*128)
#define W_OFF     0
#define WLAST_OFF 31360
#define ZERO_N    31552
#define AI_OFF    31552
#define AJ_OFF    31744
#define G_OFF     31936

// K1: h = x@weight (row in LDS); ai/aj attention dots; G = h@eu; zero W/wlast.
__global__ void k_node(const float* __restrict__ x, const float* __restrict__ w,
                       const float* __restrict__ att, const float* __restrict__ eu,
                       float* __restrict__ ws) {
    int n = blockIdx.x, c = threadIdx.x;
    __shared__ float xl[128], hl[128], r0[128], r1[128];
    xl[c] = x[n * 128 + c];
    // zero W + wlast with the whole grid (177*128 = 22656 threads)
    for (int i = n * 128 + c; i < ZERO_N; i += NN * 128) ws[i] = 0.f;
    __syncthreads();
    float acc = 0.f;
#pragma unroll 8
    for (int k = 0; k < 128; ++k) acc += xl[k] * w[k * 128 + c];
    hl[c] = acc;
    r0[c] = acc * att[c];
    r1[c] = acc * att[128 + c];
    __syncthreads();
    for (int off = 64; off > 0; off >>= 1) {
        if (c < off) { r0[c] += r0[c + off]; r1[c] += r1[c + off]; }
        __syncthreads();
    }
    if (c == 0) { ws[AI_OFF + n] = r0[0]; ws[AJ_OFF + n] = r1[0]; }
    __syncthreads();
    float acc2 = 0.f;
#pragma unroll 8
    for (int k = 0; k < 128; ++k) acc2 += hl[k] * eu[k * 128 + c];
    ws[G_OFF + n * 128 + c] = acc2;
}

// K2: single edge pass. exp(leaky(t) - M_d) with safe per-dst bound M_d;
// accumulate W[d][s] (global fp atomic, ~16 edges/cell) and wlast[d] (LDS).
__global__ void k_edge(const int* __restrict__ ei, const float* __restrict__ ea,
                       const float* __restrict__ att, float* __restrict__ ws, int E) {
    __shared__ float ail[NN], ajl[NN], llast[NN];
    int tid = threadIdx.x;
    for (int i = tid; i < NN; i += blockDim.x) {
        ail[i] = ws[AI_OFF + i];
        ajl[i] = ws[AJ_OFF + i];
        llast[i] = 0.f;
    }
    float cc = att[2 * OUTC];
    __syncthreads();
    // per-dst safe upper bound: M_d = leaky(ai[d] + ajmax + 0.6)
    float ajmax = -1e30f;
    for (int i = 0; i < NN; ++i) ajmax = fmaxf(ajmax, ajl[i]);
    float mb = ajmax + 0.6f;

    float* Wm = ws + W_OFF;
    int stride = gridDim.x * blockDim.x;
    for (int e = blockIdx.x * blockDim.x + tid; e < E; e += stride) {
        int s = ei[e];
        int d = ei[E + e];
        float eav = ea[e];
        float t = ail[d] + ajl[s] + cc * eav;
        t = (t > 0.f) ? t : NEG * t;                 // leaky
        float M = ail[d] + mb;
        M = (M > 0.f) ? M : NEG * M;                 // bound after leaky too
        float ev = __expf(t - M);
        unsafeAtomicAdd(&Wm[d * NN + s], ev);
        atomicAdd(&llast[d], ev * eav);
    }
    __syncthreads();
    for (int i = tid; i < NN; i += blockDim.x)
        unsafeAtomicAdd(&ws[WLAST_OFF + i], llast[i]);
}

// K3: out[n][c] = (W[n,:]@G[:,c] + wlast[n]*eu[128,c]) / (sum(W[n,:])+1e-16) + bias[c]
__global__ void k_out(const float* __restrict__ ws, const float* __restrict__ eu,
                      const float* __restrict__ bias, float* __restrict__ out) {
    int n = blockIdx.x, c = threadIdx.x;
    __shared__ float wl[NN];
    for (int i = c; i < 128 && i < NN; i += 128) ;  // (no-op; keep simple below)
    for (int i = c; i < NN; i += 128) wl[i] = ws[W_OFF + n * NN + i];
    __syncthreads();
    float ssum = 0.f;
    for (int s = 0; s < NN; ++s) ssum += wl[s];
    const float* G = ws + G_OFF;
    float acc = 0.f;
#pragma unroll 4
    for (int s = 0; s < NN; ++s) acc += wl[s] * G[s * 128 + c];
    float denom = ssum + 1e-16f;
    out[n * 128 + c] = (acc + ws[WLAST_OFF + n] * eu[128 * 128 + c]) / denom + bias[c];
}

extern "C" void kernel_launch(void* const* d_in, const int* in_sizes, int n_in,
                              void* d_out, int out_size, void* d_ws, size_t ws_size,
                              hipStream_t stream) {
    const float* x     = (const float*)d_in[0];
    const float* eattr = (const float*)d_in[1];
    const float* w     = (const float*)d_in[2];
    const float* att   = (const float*)d_in[3];
    const float* eu    = (const float*)d_in[4];
    const float* bias  = (const float*)d_in[5];
    const int*   ei    = (const int*)d_in[6];
    int E = in_sizes[6] / 2;
    float* ws = (float*)d_ws;

    k_node<<<NN, 128, 0, stream>>>(x, w, att, eu, ws);
    k_edge<<<EDGE_BLOCKS, EDGE_THREADS, 0, stream>>>(ei, eattr, att, ws, E);
    k_out<<<NN, 128, 0, stream>>>(ws, eu, bias, (float*)d_out);
}